// Round 2
// baseline (153.687 us; speedup 1.0000x reference)
//
#include <hip/hip_runtime.h>
#include <hip/hip_bf16.h>

#define IMG 64
#define NPTS 300
#define GRIDN 16
#define BATCH 8

typedef __hip_bfloat16 bf16;

__device__ __forceinline__ float sigm(float x) { return 1.0f / (1.0f + __expf(-x)); }
__device__ __forceinline__ float lo_bf(unsigned u) { return __uint_as_float(u << 16); }
__device__ __forceinline__ float hi_bf(unsigned u) { return __uint_as_float(u & 0xffff0000u); }

template <typename T>
__device__ __forceinline__ float ldv(const void* p, int i);
template <>
__device__ __forceinline__ float ldv<float>(const void* p, int i) { return ((const float*)p)[i]; }
template <>
__device__ __forceinline__ float ldv<bf16>(const void* p, int i) {
    return __bfloat162float(((const bf16*)p)[i]);
}

// ---------------- Kernel 0: dtype sniffer ----------------
// Reads first 1800 bf16 slots of W1 (3600 B: exactly the bf16 buffer size, half the
// fp32 one -> safe either way). True bf16 W1 ~ U(+-0.183) => max ~0.18. fp32 storage
// read as bf16 interleaves mantissa halves (random 16-bit patterns) => max >> 4.
__global__ void sniff_kernel(const void* w1, int* flag) {
    int t = threadIdx.x;
    float m = 0.0f;
    for (int i = t; i < 1800; i += 64) {
        float v = fabsf(__bfloat162float(((const bf16*)w1)[i]));
        if (!(v < 1e30f)) v = 1e30f;  // NaN/Inf -> big
        m = fmaxf(m, v);
    }
#pragma unroll
    for (int d = 1; d < 64; d <<= 1) m = fmaxf(m, __shfl_xor(m, d));
    if (t == 0) *flag = (m > 4.0f) ? 1 : 0;  // 1 => storage is fp32
}

// ---------------- Kernel A: layers 1-2 -> h2 (8 x 480 fp32) ----------------
template <typename T>
__device__ void mlp_h2_body(const void* zs, const void* W1, const void* b1, const void* W2,
                            const void* b2, float* __restrict__ h2) {
    int b = blockIdx.x, t = threadIdx.x;
    __shared__ float z[30];
    __shared__ float h1[60];
    if (t < 30) z[t] = ldv<T>(zs, b * 30 + t);
    __syncthreads();
    if (t < 60) {
        float acc = ldv<T>(b1, t);
        for (int i = 0; i < 30; ++i) acc += z[i] * ldv<T>(W1, i * 60 + t);
        h1[t] = sigm(acc);
    }
    __syncthreads();
    for (int j = t; j < 480; j += 64) {
        float acc = ldv<T>(b2, j);
        for (int i = 0; i < 60; ++i) acc += h1[i] * ldv<T>(W2, i * 480 + j);
        h2[b * 480 + j] = sigm(acc);
    }
}

__global__ void mlp_h2_kernel(const void* zs, const void* W1, const void* b1, const void* W2,
                              const void* b2, float* __restrict__ h2, const int* __restrict__ flag) {
    if (*flag)
        mlp_h2_body<float>(zs, W1, b1, W2, b2, h2);
    else
        mlp_h2_body<bf16>(zs, W1, b1, W2, b2, h2);
}

// ---------------- Kernel B: h2 @ W3 -> volumes (bf16-packed, 8 x 4096 voxels x 4ch) ----------------
template <typename T>
__device__ void mlp_w3_body(const float* __restrict__ h2, const void* W3, const void* b3,
                            bf16* __restrict__ volbf) {
    __shared__ float h2s[BATCH * 480];
    int t = threadIdx.x;
    for (int i = t; i < BATCH * 480; i += 256) h2s[i] = h2[i];
    __syncthreads();
    int j = blockIdx.x * 256 + t;
    float bj = ldv<T>(b3, j);
    float acc[BATCH];
#pragma unroll
    for (int b = 0; b < BATCH; ++b) acc[b] = bj;
    for (int i = 0; i < 480; ++i) {
        float w = ldv<T>(W3, i * 16384 + j);
#pragma unroll
        for (int b = 0; b < BATCH; ++b) acc[b] = fmaf(h2s[b * 480 + i], w, acc[b]);
    }
    int c = j >> 12;   // channel 0..3 (0=sigma,1..3=rgb)
    int v = j & 4095;  // voxel z*256+y*16+x
#pragma unroll
    for (int b = 0; b < BATCH; ++b)
        volbf[(size_t)(b * 4096 + v) * 4 + c] = __float2bfloat16(sigm(acc[b]));
}

__global__ void mlp_w3_kernel(const float* __restrict__ h2, const void* W3, const void* b3,
                              bf16* __restrict__ volbf, const int* __restrict__ flag) {
    if (*flag)
        mlp_w3_body<float>(h2, W3, b3, volbf);
    else
        mlp_w3_body<bf16>(h2, W3, b3, volbf);
}

// ---------------- Kernel C: ray render ----------------
// 512 blocks x 256 thr. Block = 64 rays of one image; lane = ray*4 + seg (4 depth segments).
// LDS: 4096 voxels x uint2 (4 packed bf16: sigma,r | g,b) = 32 KB.
__global__ __launch_bounds__(256) void render_kernel(const void* Rm, const void* Tm,
                                                     const bf16* __restrict__ volbf, void* out,
                                                     const int* __restrict__ flag) {
    __shared__ uint2 vox[4096];
    int t = threadIdx.x;
    int rayBase = blockIdx.x * 64;
    int b = rayBase >> 12;
    const uint2* src = (const uint2*)(volbf + (size_t)b * 4096 * 4);
    for (int i = t; i < 4096; i += 256) vox[i] = src[i];
    __syncthreads();

    int f32out = *flag;
    int ray = rayBase + (t >> 2);
    int seg = t & 3;
    int pix = ray & 4095;
    int h = pix >> 6, w = pix & 63;

    const float inv_f = 0.57735026919f;  // tan(30deg)
    float dcx = (0.984375f - 0.03125f * (float)w) * inv_f;
    float dcy = (0.984375f - 0.03125f * (float)h) * inv_f;

    float R[9], Tv[3];
    if (f32out) {
#pragma unroll
        for (int i = 0; i < 9; ++i) R[i] = ((const float*)Rm)[b * 9 + i];
#pragma unroll
        for (int i = 0; i < 3; ++i) Tv[i] = ((const float*)Tm)[b * 3 + i];
    } else {
#pragma unroll
        for (int i = 0; i < 9; ++i) R[i] = __bfloat162float(((const bf16*)Rm)[b * 9 + i]);
#pragma unroll
        for (int i = 0; i < 3; ++i) Tv[i] = __bfloat162float(((const bf16*)Tm)[b * 3 + i]);
    }

    // dirs_w[d] = sum_c dir_cam[c] * R[d][c];  origin[d] = -sum_c T[c]*R[d][c]
    float dx_ = dcx * R[0] + dcy * R[1] + R[2];
    float dy_ = dcx * R[3] + dcy * R[4] + R[5];
    float dz_ = dcx * R[6] + dcy * R[7] + R[8];
    float ox = -(Tv[0] * R[0] + Tv[1] * R[1] + Tv[2] * R[2]);
    float oy = -(Tv[0] * R[3] + Tv[1] * R[4] + Tv[2] * R[5]);
    float oz = -(Tv[0] * R[6] + Tv[1] * R[7] + Tv[2] * R[8]);

    // slab: contribution possible only while |world coord| < 0.85 on every axis
    // (ix = p*10+7.5 in (-1,16) <=> |p| < 0.85)
    float tA = -1e30f, tB = 1e30f;
    bool miss = false;
    {
        float dd[3] = {dx_, dy_, dz_}, oo[3] = {ox, oy, oz};
#pragma unroll
        for (int a = 0; a < 3; ++a) {
            if (fabsf(dd[a]) > 1e-8f) {
                float inv = 1.0f / dd[a];
                float ra = (-0.85f - oo[a]) * inv, rb = (0.85f - oo[a]) * inv;
                tA = fmaxf(tA, fminf(ra, rb));
                tB = fminf(tB, fmaxf(ra, rb));
            } else if (fabsf(oo[a]) >= 0.85f) {
                miss = true;
            }
        }
    }
    const float step = 2.9f / 299.0f;
    const float inv_step = 299.0f / 2.9f;
    int ilo = 0, ihi = -1;
    if (!miss && tB > tA) {
        float flo = fmaxf(-2.0f, fminf(302.0f, ceilf((tA - 0.1f) * inv_step)));
        float fhi = fmaxf(-2.0f, fminf(302.0f, floorf((tB - 0.1f) * inv_step)));
        ilo = (int)flo - 1;  // widen 1 step each side; out-of-grid samples contribute exactly 0
        ihi = (int)fhi + 1;
        if (ilo < 0) ilo = 0;
        if (ihi > 299) ihi = 299;
    }
    int n = ihi - ilo + 1;
    if (n < 0) n = 0;
    int s0 = ilo + (n * seg) / 4;
    int s1 = ilo + (n * (seg + 1)) / 4;

    float cr = 0.f, cg = 0.f, cb = 0.f, Pa = 1.f, Po = 1.f;
    for (int i = s0; i < s1; ++i) {
        float tt = 0.1f + step * (float)i;
        float ix = fmaf(fmaf(tt, dx_, ox), 10.0f, 7.5f);
        float iy = fmaf(fmaf(tt, dy_, oy), 10.0f, 7.5f);
        float iz = fmaf(fmaf(tt, dz_, oz), 10.0f, 7.5f);
        float fx = floorf(ix), fy = floorf(iy), fz = floorf(iz);
        float txf = ix - fx, tyf = iy - fy, tzf = iz - fz;
        int x0 = (int)fx, y0 = (int)fy, z0 = (int)fz;
        float wx0 = (x0 >= 0 && x0 <= 15) ? (1.0f - txf) : 0.0f;
        float wx1 = (x0 >= -1 && x0 <= 14) ? txf : 0.0f;
        float wy0 = (y0 >= 0 && y0 <= 15) ? (1.0f - tyf) : 0.0f;
        float wy1 = (y0 >= -1 && y0 <= 14) ? tyf : 0.0f;
        float wz0 = (z0 >= 0 && z0 <= 15) ? (1.0f - tzf) : 0.0f;
        float wz1 = (z0 >= -1 && z0 <= 14) ? tzf : 0.0f;
        int xi0 = min(max(x0, 0), 15), xi1 = min(max(x0 + 1, 0), 15);
        int yi0 = min(max(y0, 0), 15), yi1 = min(max(y0 + 1, 0), 15);
        int zi0 = min(max(z0, 0), 15), zi1 = min(max(z0 + 1, 0), 15);

        float sx = 0.f, sr = 0.f, sg = 0.f, sb = 0.f;
#define CORN(W, ZI, YI, XI)                                 \
    {                                                       \
        uint2 q = vox[((ZI) << 8) + ((YI) << 4) + (XI)];    \
        sx = fmaf((W), lo_bf(q.x), sx);                     \
        sr = fmaf((W), hi_bf(q.x), sr);                     \
        sg = fmaf((W), lo_bf(q.y), sg);                     \
        sb = fmaf((W), hi_bf(q.y), sb);                     \
    }
        float wxy00 = wx0 * wy0, wxy10 = wx1 * wy0, wxy01 = wx0 * wy1, wxy11 = wx1 * wy1;
        CORN(wxy00 * wz0, zi0, yi0, xi0)
        CORN(wxy10 * wz0, zi0, yi0, xi1)
        CORN(wxy01 * wz0, zi0, yi1, xi0)
        CORN(wxy11 * wz0, zi0, yi1, xi1)
        CORN(wxy00 * wz1, zi1, yi0, xi0)
        CORN(wxy10 * wz1, zi1, yi0, xi1)
        CORN(wxy01 * wz1, zi1, yi1, xi0)
        CORN(wxy11 * wz1, zi1, yi1, xi1)
#undef CORN

        float wgt = sx * Pa;
        cr = fmaf(wgt, sr, cr);
        cg = fmaf(wgt, sg, cg);
        cb = fmaf(wgt, sb, cb);
        Pa *= (1.0f - sx);  // 1+1e-10-sx: the 1e-10 vanishes in fp32
        Po *= (1.0f - sx);
    }

    // combine the 4 depth segments (ordered compose) within each 4-lane group
#pragma unroll
    for (int d = 1; d < 4; d <<= 1) {
        float o_cr = __shfl_xor(cr, d);
        float o_cg = __shfl_xor(cg, d);
        float o_cb = __shfl_xor(cb, d);
        float o_Pa = __shfl_xor(Pa, d);
        float o_Po = __shfl_xor(Po, d);
        bool first = ((seg & d) == 0);
        cr = first ? fmaf(Pa, o_cr, cr) : fmaf(o_Pa, cr, o_cr);
        cg = first ? fmaf(Pa, o_cg, cg) : fmaf(o_Pa, cg, o_cg);
        cb = first ? fmaf(Pa, o_cb, cb) : fmaf(o_Pa, cb, o_cb);
        Pa *= o_Pa;
        Po *= o_Po;
    }

    if (seg == 0) {
        if (f32out) {
            float* of = (float*)out;
            of[ray] = 1.0f - Po;
            float* orgb = of + BATCH * IMG * IMG;
            orgb[ray * 3 + 0] = cr;
            orgb[ray * 3 + 1] = cg;
            orgb[ray * 3 + 2] = cb;
        } else {
            bf16* ob = (bf16*)out;
            ob[ray] = __float2bfloat16(1.0f - Po);
            bf16* orgb = ob + BATCH * IMG * IMG;
            orgb[ray * 3 + 0] = __float2bfloat16(cr);
            orgb[ray * 3 + 1] = __float2bfloat16(cg);
            orgb[ray * 3 + 2] = __float2bfloat16(cb);
        }
    }
}

extern "C" void kernel_launch(void* const* d_in, const int* in_sizes, int n_in,
                              void* d_out, int out_size, void* d_ws, size_t ws_size,
                              hipStream_t stream) {
    const void* zs = d_in[0];
    const void* W1 = d_in[1];
    const void* b1 = d_in[2];
    const void* W2 = d_in[3];
    const void* b2 = d_in[4];
    const void* W3 = d_in[5];
    const void* b3 = d_in[6];
    const void* Rm = d_in[7];
    const void* Tm = d_in[8];

    // ws layout: volbf16 [0, 262144) | h2 fp32 [262144, 277504) | flag [277504, 277508)
    bf16* volbf = (bf16*)d_ws;
    float* h2 = (float*)((char*)d_ws + 262144);
    int* flag = (int*)((char*)d_ws + 277504);

    hipLaunchKernelGGL(sniff_kernel, dim3(1), dim3(64), 0, stream, W1, flag);
    hipLaunchKernelGGL(mlp_h2_kernel, dim3(BATCH), dim3(64), 0, stream, zs, W1, b1, W2, b2, h2, flag);
    hipLaunchKernelGGL(mlp_w3_kernel, dim3(64), dim3(256), 0, stream, h2, W3, b3, volbf, flag);
    hipLaunchKernelGGL(render_kernel, dim3(512), dim3(256), 0, stream, Rm, Tm, volbf, d_out, flag);
}

// Round 3
// 130.026 us; speedup vs baseline: 1.1820x; 1.1820x over previous
//
#include <hip/hip_runtime.h>
#include <hip/hip_bf16.h>

#define IMG 64
#define NPTS 300
#define GRIDN 16
#define BATCH 8

typedef __hip_bfloat16 bf16;

__device__ __forceinline__ float sigm(float x) { return 1.0f / (1.0f + __expf(-x)); }
__device__ __forceinline__ float lo_bf(unsigned u) { return __uint_as_float(u << 16); }
__device__ __forceinline__ float hi_bf(unsigned u) { return __uint_as_float(u & 0xffff0000u); }
__device__ __forceinline__ float us_bf(unsigned short u) {
    return __uint_as_float(((unsigned)u) << 16);
}

template <typename T>
__device__ __forceinline__ float ldv(const void* p, int i);
template <>
__device__ __forceinline__ float ldv<float>(const void* p, int i) { return ((const float*)p)[i]; }
template <>
__device__ __forceinline__ float ldv<bf16>(const void* p, int i) {
    return __bfloat162float(((const bf16*)p)[i]);
}

// ---------------- Kernel A: sniff dtype + layers 1-2 -> h2 (8 x 480 fp32) ----------------
template <typename T>
__device__ void mlp_h2_body(const void* zs, const void* W1, const void* b1, const void* W2,
                            const void* b2, float* __restrict__ h2) {
    int b = blockIdx.x, t = threadIdx.x;
    __shared__ float z[30];
    __shared__ float h1[60];
    if (t < 30) z[t] = ldv<T>(zs, b * 30 + t);
    __syncthreads();
    if (t < 60) {
        float acc = ldv<T>(b1, t);
        for (int i = 0; i < 30; ++i) acc += z[i] * ldv<T>(W1, i * 60 + t);
        h1[t] = sigm(acc);
    }
    __syncthreads();
    for (int j = t; j < 480; j += 64) {
        float acc = ldv<T>(b2, j);
        for (int i = 0; i < 60; ++i) acc += h1[i] * ldv<T>(W2, i * 480 + j);
        h2[b * 480 + j] = sigm(acc);
    }
}

// Inline sniffer: first 1800 bf16 slots of W1 (3600 B = the bf16 buffer size, half the fp32
// one -> safe either way). bf16 W1 ~ U(+-0.183) => max ~0.18; fp32 storage read as bf16 has
// random low-half exponents => max >> 4 (whp over 900 samples).
__global__ void mlp_h2_kernel(const void* zs, const void* W1, const void* b1, const void* W2,
                              const void* b2, float* __restrict__ h2, int* __restrict__ flag) {
    int t = threadIdx.x;
    float m = 0.0f;
    for (int i = t; i < 1800; i += 64) {
        float v = fabsf(__bfloat162float(((const bf16*)W1)[i]));
        if (!(v < 1e30f)) v = 1e30f;
        m = fmaxf(m, v);
    }
#pragma unroll
    for (int d = 1; d < 64; d <<= 1) m = fmaxf(m, __shfl_xor(m, d));
    int f = (m > 4.0f) ? 1 : 0;
    if (blockIdx.x == 0 && t == 0) *flag = f;
    if (f)
        mlp_h2_body<float>(zs, W1, b1, W2, b2, h2);
    else
        mlp_h2_body<bf16>(zs, W1, b1, W2, b2, h2);
}

// ---------------- Kernel B1: K-split partial GEMM  h2 @ W3 ----------------
// grid (16 jblocks, 16 kslices) x 256 thr. Thread owns 4 consecutive columns (ushort4 /
// float4 loads), 30 rows, 8 batches -> 32 fp32 accumulators. partial[(s*8+b)*16384 + j].
template <typename T>
__device__ void w3_partial_body(const float* __restrict__ h2, const void* W3,
                                float* __restrict__ partial) {
    __shared__ float h2s[BATCH][30];
    int t = threadIdx.x;
    int jb = blockIdx.x, s = blockIdx.y;
    int i0 = s * 30;
    if (t < 240) {
        int b = t / 30, i = t - b * 30;
        h2s[b][i] = h2[b * 480 + i0 + i];
    }
    __syncthreads();
    int j0 = jb * 1024 + t * 4;
    float acc[BATCH][4];
#pragma unroll
    for (int b = 0; b < BATCH; ++b)
#pragma unroll
        for (int c = 0; c < 4; ++c) acc[b][c] = 0.0f;

#pragma unroll 6
    for (int i = 0; i < 30; ++i) {
        float w0, w1, w2, w3v;
        if (sizeof(T) == 2) {
            ushort4 q = *(const ushort4*)((const unsigned short*)W3 + (size_t)(i0 + i) * 16384 + j0);
            w0 = us_bf(q.x); w1 = us_bf(q.y); w2 = us_bf(q.z); w3v = us_bf(q.w);
        } else {
            float4 q = *(const float4*)((const float*)W3 + (size_t)(i0 + i) * 16384 + j0);
            w0 = q.x; w1 = q.y; w2 = q.z; w3v = q.w;
        }
#pragma unroll
        for (int b = 0; b < BATCH; ++b) {
            float h = h2s[b][i];
            acc[b][0] = fmaf(h, w0, acc[b][0]);
            acc[b][1] = fmaf(h, w1, acc[b][1]);
            acc[b][2] = fmaf(h, w2, acc[b][2]);
            acc[b][3] = fmaf(h, w3v, acc[b][3]);
        }
    }
#pragma unroll
    for (int b = 0; b < BATCH; ++b) {
        float4 st = {acc[b][0], acc[b][1], acc[b][2], acc[b][3]};
        *(float4*)(partial + ((size_t)(s * BATCH + b) << 14) + j0) = st;
    }
}

__global__ __launch_bounds__(256) void w3_partial_kernel(const float* __restrict__ h2,
                                                         const void* W3,
                                                         float* __restrict__ partial,
                                                         const int* __restrict__ flag) {
    if (*flag)
        w3_partial_body<float>(h2, W3, partial);
    else
        w3_partial_body<bf16>(h2, W3, partial);
}

// ---------------- Kernel B2: reduce 16 partials + bias -> sigmoid -> packed bf16 volume ----
__global__ __launch_bounds__(256) void w3_reduce_kernel(const float* __restrict__ partial,
                                                        const void* b3, bf16* __restrict__ volbf,
                                                        const int* __restrict__ flag) {
    int tid = blockIdx.x * 256 + threadIdx.x;  // 131072 = 8 batches x 16384 cols
    int b = tid >> 14, j = tid & 16383;
    float a = 0.0f;
#pragma unroll
    for (int s = 0; s < 16; ++s) a += partial[((size_t)(s * BATCH + b) << 14) + j];
    a += (*flag) ? ldv<float>(b3, j) : ldv<bf16>(b3, j);
    a = sigm(a);
    int c = j >> 12, v = j & 4095;
    volbf[(size_t)((b << 12) + v) * 4 + c] = __float2bfloat16(a);
}

// ---------------- Fallback Kernel B (monolithic, used when ws is small) ----------------
template <typename T>
__device__ void mlp_w3_body(const float* __restrict__ h2, const void* W3, const void* b3,
                            bf16* __restrict__ volbf) {
    __shared__ float h2s[BATCH * 480];
    int t = threadIdx.x;
    for (int i = t; i < BATCH * 480; i += 256) h2s[i] = h2[i];
    __syncthreads();
    int j = blockIdx.x * 256 + t;
    float bj = ldv<T>(b3, j);
    float acc[BATCH];
#pragma unroll
    for (int b = 0; b < BATCH; ++b) acc[b] = bj;
    for (int i = 0; i < 480; ++i) {
        float w = ldv<T>(W3, i * 16384 + j);
#pragma unroll
        for (int b = 0; b < BATCH; ++b) acc[b] = fmaf(h2s[b * 480 + i], w, acc[b]);
    }
    int c = j >> 12;
    int v = j & 4095;
#pragma unroll
    for (int b = 0; b < BATCH; ++b)
        volbf[(size_t)(b * 4096 + v) * 4 + c] = __float2bfloat16(sigm(acc[b]));
}

__global__ void mlp_w3_kernel(const float* __restrict__ h2, const void* W3, const void* b3,
                              bf16* __restrict__ volbf, const int* __restrict__ flag) {
    if (*flag)
        mlp_w3_body<float>(h2, W3, b3, volbf);
    else
        mlp_w3_body<bf16>(h2, W3, b3, volbf);
}

// ---------------- Kernel C: ray render ----------------
// 512 blocks x 256 thr. Block = 64 rays of one image; lane = ray*4 + seg (4 depth segments).
// LDS: 4096 voxels x uint2 (4 packed bf16: sigma,r | g,b) = 32 KB.
__global__ __launch_bounds__(256) void render_kernel(const void* Rm, const void* Tm,
                                                     const bf16* __restrict__ volbf, void* out,
                                                     const int* __restrict__ flag) {
    __shared__ uint2 vox[4096];
    int t = threadIdx.x;
    int rayBase = blockIdx.x * 64;
    int b = rayBase >> 12;
    const uint2* src = (const uint2*)(volbf + (size_t)b * 4096 * 4);
    for (int i = t; i < 4096; i += 256) vox[i] = src[i];
    __syncthreads();

    int f32out = *flag;
    int ray = rayBase + (t >> 2);
    int seg = t & 3;
    int pix = ray & 4095;
    int h = pix >> 6, w = pix & 63;

    const float inv_f = 0.57735026919f;  // tan(30deg)
    float dcx = (0.984375f - 0.03125f * (float)w) * inv_f;
    float dcy = (0.984375f - 0.03125f * (float)h) * inv_f;

    float R[9], Tv[3];
    if (f32out) {
#pragma unroll
        for (int i = 0; i < 9; ++i) R[i] = ((const float*)Rm)[b * 9 + i];
#pragma unroll
        for (int i = 0; i < 3; ++i) Tv[i] = ((const float*)Tm)[b * 3 + i];
    } else {
#pragma unroll
        for (int i = 0; i < 9; ++i) R[i] = __bfloat162float(((const bf16*)Rm)[b * 9 + i]);
#pragma unroll
        for (int i = 0; i < 3; ++i) Tv[i] = __bfloat162float(((const bf16*)Tm)[b * 3 + i]);
    }

    float dx_ = dcx * R[0] + dcy * R[1] + R[2];
    float dy_ = dcx * R[3] + dcy * R[4] + R[5];
    float dz_ = dcx * R[6] + dcy * R[7] + R[8];
    float ox = -(Tv[0] * R[0] + Tv[1] * R[1] + Tv[2] * R[2]);
    float oy = -(Tv[0] * R[3] + Tv[1] * R[4] + Tv[2] * R[5]);
    float oz = -(Tv[0] * R[6] + Tv[1] * R[7] + Tv[2] * R[8]);

    // slab: contribution possible only while |world coord| < 0.85 on every axis
    float tA = -1e30f, tB = 1e30f;
    bool miss = false;
    {
        float dd[3] = {dx_, dy_, dz_}, oo[3] = {ox, oy, oz};
#pragma unroll
        for (int a = 0; a < 3; ++a) {
            if (fabsf(dd[a]) > 1e-8f) {
                float inv = 1.0f / dd[a];
                float ra = (-0.85f - oo[a]) * inv, rb = (0.85f - oo[a]) * inv;
                tA = fmaxf(tA, fminf(ra, rb));
                tB = fminf(tB, fmaxf(ra, rb));
            } else if (fabsf(oo[a]) >= 0.85f) {
                miss = true;
            }
        }
    }
    const float step = 2.9f / 299.0f;
    const float inv_step = 299.0f / 2.9f;
    int ilo = 0, ihi = -1;
    if (!miss && tB > tA) {
        float flo = fmaxf(-2.0f, fminf(302.0f, ceilf((tA - 0.1f) * inv_step)));
        float fhi = fmaxf(-2.0f, fminf(302.0f, floorf((tB - 0.1f) * inv_step)));
        ilo = (int)flo - 1;  // widen 1 step each side; out-of-grid samples contribute exactly 0
        ihi = (int)fhi + 1;
        if (ilo < 0) ilo = 0;
        if (ihi > 299) ihi = 299;
    }
    int n = ihi - ilo + 1;
    if (n < 0) n = 0;
    int s0 = ilo + (n * seg) / 4;
    int s1 = ilo + (n * (seg + 1)) / 4;

    float cr = 0.f, cg = 0.f, cb = 0.f, Pa = 1.f;
    for (int i = s0; i < s1; ++i) {
        float tt = 0.1f + step * (float)i;
        float ix = fmaf(fmaf(tt, dx_, ox), 10.0f, 7.5f);
        float iy = fmaf(fmaf(tt, dy_, oy), 10.0f, 7.5f);
        float iz = fmaf(fmaf(tt, dz_, oz), 10.0f, 7.5f);
        float fx = floorf(ix), fy = floorf(iy), fz = floorf(iz);
        float txf = ix - fx, tyf = iy - fy, tzf = iz - fz;
        int x0 = (int)fx, y0 = (int)fy, z0 = (int)fz;
        float wx0 = (x0 >= 0 && x0 <= 15) ? (1.0f - txf) : 0.0f;
        float wx1 = (x0 >= -1 && x0 <= 14) ? txf : 0.0f;
        float wy0 = (y0 >= 0 && y0 <= 15) ? (1.0f - tyf) : 0.0f;
        float wy1 = (y0 >= -1 && y0 <= 14) ? tyf : 0.0f;
        float wz0 = (z0 >= 0 && z0 <= 15) ? (1.0f - tzf) : 0.0f;
        float wz1 = (z0 >= -1 && z0 <= 14) ? tzf : 0.0f;
        int xi0 = min(max(x0, 0), 15), xi1 = min(max(x0 + 1, 0), 15);
        int yi0 = min(max(y0, 0), 15), yi1 = min(max(y0 + 1, 0), 15);
        int zi0 = min(max(z0, 0), 15), zi1 = min(max(z0 + 1, 0), 15);

        float sx = 0.f, sr = 0.f, sg = 0.f, sb = 0.f;
#define CORN(W, ZI, YI, XI)                              \
    {                                                    \
        uint2 q = vox[((ZI) << 8) + ((YI) << 4) + (XI)]; \
        sx = fmaf((W), lo_bf(q.x), sx);                  \
        sr = fmaf((W), hi_bf(q.x), sr);                  \
        sg = fmaf((W), lo_bf(q.y), sg);                  \
        sb = fmaf((W), hi_bf(q.y), sb);                  \
    }
        float wxy00 = wx0 * wy0, wxy10 = wx1 * wy0, wxy01 = wx0 * wy1, wxy11 = wx1 * wy1;
        CORN(wxy00 * wz0, zi0, yi0, xi0)
        CORN(wxy10 * wz0, zi0, yi0, xi1)
        CORN(wxy01 * wz0, zi0, yi1, xi0)
        CORN(wxy11 * wz0, zi0, yi1, xi1)
        CORN(wxy00 * wz1, zi1, yi0, xi0)
        CORN(wxy10 * wz1, zi1, yi0, xi1)
        CORN(wxy01 * wz1, zi1, yi1, xi0)
        CORN(wxy11 * wz1, zi1, yi1, xi1)
#undef CORN

        float wgt = sx * Pa;
        cr = fmaf(wgt, sr, cr);
        cg = fmaf(wgt, sg, cg);
        cb = fmaf(wgt, sb, cb);
        Pa *= (1.0f - sx);  // 1+1e-10-sx: the 1e-10 vanishes in fp32; opacity prod is identical
    }

    // compose the 4 depth segments (ordered) within each 4-lane group
#pragma unroll
    for (int d = 1; d < 4; d <<= 1) {
        float o_cr = __shfl_xor(cr, d);
        float o_cg = __shfl_xor(cg, d);
        float o_cb = __shfl_xor(cb, d);
        float o_Pa = __shfl_xor(Pa, d);
        bool first = ((seg & d) == 0);
        cr = first ? fmaf(Pa, o_cr, cr) : fmaf(o_Pa, cr, o_cr);
        cg = first ? fmaf(Pa, o_cg, cg) : fmaf(o_Pa, cg, o_cg);
        cb = first ? fmaf(Pa, o_cb, cb) : fmaf(o_Pa, cb, o_cb);
        Pa *= o_Pa;
    }

    if (seg == 0) {
        if (f32out) {
            float* of = (float*)out;
            of[ray] = 1.0f - Pa;
            float* orgb = of + BATCH * IMG * IMG;
            orgb[ray * 3 + 0] = cr;
            orgb[ray * 3 + 1] = cg;
            orgb[ray * 3 + 2] = cb;
        } else {
            bf16* ob = (bf16*)out;
            ob[ray] = __float2bfloat16(1.0f - Pa);
            bf16* orgb = ob + BATCH * IMG * IMG;
            orgb[ray * 3 + 0] = __float2bfloat16(cr);
            orgb[ray * 3 + 1] = __float2bfloat16(cg);
            orgb[ray * 3 + 2] = __float2bfloat16(cb);
        }
    }
}

extern "C" void kernel_launch(void* const* d_in, const int* in_sizes, int n_in,
                              void* d_out, int out_size, void* d_ws, size_t ws_size,
                              hipStream_t stream) {
    const void* zs = d_in[0];
    const void* W1 = d_in[1];
    const void* b1 = d_in[2];
    const void* W2 = d_in[3];
    const void* b2 = d_in[4];
    const void* W3 = d_in[5];
    const void* b3 = d_in[6];
    const void* Rm = d_in[7];
    const void* Tm = d_in[8];

    const size_t PARTIAL_BYTES = (size_t)16 * BATCH * 16384 * 4;  // 8 MB
    const size_t NEED = 262144 + PARTIAL_BYTES + 15360 + 64;

    bf16* volbf = (bf16*)d_ws;
    if (ws_size >= NEED) {
        float* partial = (float*)((char*)d_ws + 262144);
        float* h2 = (float*)((char*)d_ws + 262144 + PARTIAL_BYTES);
        int* flag = (int*)((char*)d_ws + 262144 + PARTIAL_BYTES + 15360);
        hipLaunchKernelGGL(mlp_h2_kernel, dim3(BATCH), dim3(64), 0, stream, zs, W1, b1, W2, b2,
                           h2, flag);
        hipLaunchKernelGGL(w3_partial_kernel, dim3(16, 16), dim3(256), 0, stream, h2, W3,
                           partial, flag);
        hipLaunchKernelGGL(w3_reduce_kernel, dim3(512), dim3(256), 0, stream, partial, b3,
                           volbf, flag);
        hipLaunchKernelGGL(render_kernel, dim3(512), dim3(256), 0, stream, Rm, Tm, volbf, d_out,
                           flag);
    } else {
        float* h2 = (float*)((char*)d_ws + 262144);
        int* flag = (int*)((char*)d_ws + 277504);
        hipLaunchKernelGGL(mlp_h2_kernel, dim3(BATCH), dim3(64), 0, stream, zs, W1, b1, W2, b2,
                           h2, flag);
        hipLaunchKernelGGL(mlp_w3_kernel, dim3(64), dim3(256), 0, stream, h2, W3, b3, volbf,
                           flag);
        hipLaunchKernelGGL(render_kernel, dim3(512), dim3(256), 0, stream, Rm, Tm, volbf, d_out,
                           flag);
    }
}